// Round 17
// baseline (411.812 us; speedup 1.0000x reference)
//
#include <hip/hip_runtime.h>
#include <hip/hip_bf16.h>

typedef __attribute__((ext_vector_type(8))) short short8;
typedef __attribute__((ext_vector_type(4))) float f32x4;

#define LDW 40   // conv LDS row pitch in ushorts (80 B)

__device__ __forceinline__ unsigned short f2bf(float f) {
  __hip_bfloat16 h = __float2bfloat16(f);
  return *(unsigned short*)&h;
}
__device__ __forceinline__ float bf2f(unsigned h) {
  return __uint_as_float(h << 16);
}
__device__ __forceinline__ unsigned pk2(float a, float b) {
  return (unsigned)f2bf(a) | ((unsigned)f2bf(b) << 16);
}
__device__ __forceinline__ unsigned long long pack4(float a, float b, float c, float d) {
  return (unsigned long long)pk2(a, b) | ((unsigned long long)pk2(c, d) << 32);
}

// ---------------- prep: w -> bf16, zero S0+bn_acc+e_acc
__global__ __launch_bounds__(256) void prep(const float* __restrict__ w,
    unsigned short* __restrict__ w_bf, float* __restrict__ S0, float* __restrict__ e_acc) {
  int i = blockIdx.x * 256 + threadIdx.x;
  float4 v = ((const float4*)w)[i];
  *(unsigned long long*)(w_bf + 4 * i) = pack4(v.x, v.y, v.z, v.w);
  e_acc[2 * i] = 0.f;
  e_acc[2 * i + 1] = 0.f;
  if (blockIdx.x == 0) {
    S0[threadIdx.x] = 0.f;
    S0[256 + threadIdx.x] = 0.f;
  }
}

// ---------------- probe helper: re-zero S0 + e_acc between encode relaunches
// (bn_acc is NOT touched — encode reads it)
__global__ __launch_bounds__(256) void zero_se(float* __restrict__ S0,
    float* __restrict__ e_acc) {
  int i = blockIdx.x * 256 + threadIdx.x;   // 128 blocks x 256 = 32768
  e_acc[i] = 0.f;
  if (blockIdx.x == 0) S0[threadIdx.x] = 0.f;
}

// ---------------- Phase 1: conv as bf16 MFMA GEMM (round-8 exact), y bf16 [b][d][n]
__global__ __launch_bounds__(256) void conv_mfma(const float* __restrict__ x,
    const unsigned short* __restrict__ w_bf, const float* __restrict__ bias,
    unsigned short* __restrict__ y, float* __restrict__ bn_acc) {
  const int b = blockIdx.y;
  const int n0 = blockIdx.x * 128;
  const int tid = threadIdx.x;
  const int lane = tid & 63, wv = tid >> 6;
  const int li = lane & 15, q = lane >> 4;
  __shared__ unsigned short Wl[128 * LDW];
  __shared__ unsigned short Xl[128 * LDW];
  f32x4 acc[2][8];
#pragma unroll
  for (int m = 0; m < 2; ++m)
#pragma unroll
    for (int r = 0; r < 8; ++r) acc[m][r] = (f32x4){0.f, 0.f, 0.f, 0.f};
  const float* xb = x + (size_t)b * (512 * 4096) + n0;
  const int nq = tid & 31, cgp = tid >> 5;
  for (int c0 = 0; c0 < 512; c0 += 32) {
#pragma unroll
    for (int i = 0; i < 2; ++i) {
      int idx = tid + i * 256;
      int d = idx >> 2, hh = idx & 3;
      *(short8*)&Wl[d * LDW + hh * 8] = *(const short8*)(w_bf + (size_t)d * 512 + c0 + hh * 8);
    }
    {
      const float* xp = xb + (size_t)(c0 + cgp * 4) * 4096 + nq * 4;
      float4 v0 = *(const float4*)(xp);
      float4 v1 = *(const float4*)(xp + 4096);
      float4 v2 = *(const float4*)(xp + 2 * 4096);
      float4 v3 = *(const float4*)(xp + 3 * 4096);
      const float* a0 = (const float*)&v0;
      const float* a1 = (const float*)&v1;
      const float* a2 = (const float*)&v2;
      const float* a3 = (const float*)&v3;
#pragma unroll
      for (int j = 0; j < 4; ++j) {
        *(unsigned long long*)&Xl[(nq * 4 + j) * LDW + cgp * 4] =
            pack4(a0[j], a1[j], a2[j], a3[j]);
      }
    }
    __syncthreads();
    short8 af[2], bfr[8];
#pragma unroll
    for (int m = 0; m < 2; ++m)
      af[m] = *(const short8*)&Xl[(32 * wv + 16 * m + li) * LDW + q * 8];
#pragma unroll
    for (int r = 0; r < 8; ++r)
      bfr[r] = *(const short8*)&Wl[(16 * r + li) * LDW + q * 8];
#pragma unroll
    for (int m = 0; m < 2; ++m)
#pragma unroll
      for (int r = 0; r < 8; ++r)
        acc[m][r] = __builtin_amdgcn_mfma_f32_16x16x32_bf16(af[m], bfr[r], acc[m][r], 0, 0, 0);
    __syncthreads();
  }
  float s1[8], s2[8];
#pragma unroll
  for (int r = 0; r < 8; ++r) { s1[r] = 0.f; s2[r] = 0.f; }
#pragma unroll
  for (int r = 0; r < 8; ++r) {
    int d = 16 * r + li;
    float bb = bias[d];
#pragma unroll
    for (int m = 0; m < 2; ++m) {
      int nl = 32 * wv + 16 * m + 4 * q;
      float v0 = acc[m][r][0] + bb, v1 = acc[m][r][1] + bb;
      float v2 = acc[m][r][2] + bb, v3 = acc[m][r][3] + bb;
      s1[r] += v0 + v1 + v2 + v3;
      s2[r] += v0 * v0 + v1 * v1 + v2 * v2 + v3 * v3;
      *(unsigned long long*)(y + ((size_t)(b * 128 + d)) * 4096 + n0 + nl) =
          pack4(v0, v1, v2, v3);
    }
  }
#pragma unroll
  for (int r = 0; r < 8; ++r) {
    s1[r] += __shfl_xor(s1[r], 16); s1[r] += __shfl_xor(s1[r], 32);
    s2[r] += __shfl_xor(s2[r], 16); s2[r] += __shfl_xor(s2[r], 32);
  }
  float* red = (float*)Wl;
  if (lane < 16) {
#pragma unroll
    for (int r = 0; r < 8; ++r) {
      red[0 * 512 + wv * 128 + r * 16 + li] = s1[r];
      red[1 * 512 + wv * 128 + r * 16 + li] = s2[r];
    }
  }
  __syncthreads();
  {
    int s = tid >> 7, d = tid & 127;
    float v = red[s * 512 + d] + red[s * 512 + 128 + d]
            + red[s * 512 + 256 + d] + red[s * 512 + 384 + d];
    atomicAdd(&bn_acc[s * 128 + d], v);
  }
}

// ---------------- Phase 2 (fused assign+aggregate): round-8 exact
__global__ __launch_bounds__(128) void encode(const unsigned short* __restrict__ y,
    const float* __restrict__ bn_acc, const float* __restrict__ bn_g,
    const float* __restrict__ bn_b, const float* __restrict__ cw,
    const float* __restrict__ scale, float* __restrict__ e_acc, float* __restrict__ S0) {
  const int b = blockIdx.y;
  const int n0 = blockIdx.x * 128;
  const int tid = threadIdx.x;
  const int lane = tid & 63, wv = tid >> 6;
  __shared__ unsigned short Xt[128 * 128];
  __shared__ unsigned short Pt[16 * 128];
  __shared__ float cws[16][128];
  __shared__ float c2s[16], scs[128], shs[128], sscale[16];
  for (int i = tid; i < 2048; i += 128) cws[i >> 7][i & 127] = cw[i];
  {
    float mu = bn_acc[tid] * (1.f / 65536.f);
    float var = bn_acc[128 + tid] * (1.f / 65536.f) - mu * mu;
    float sc = rsqrtf(var + 1e-5f) * bn_g[tid];
    scs[tid] = sc;
    shs[tid] = bn_b[tid] - mu * sc;
  }
  if (tid < 16) sscale[tid] = scale[tid];
  __syncthreads();
  if (tid < 16) {
    float s = 0.f;
#pragma unroll
    for (int d = 0; d < 128; ++d) s += cws[tid][d] * cws[tid][d];
    c2s[tid] = s;
  }
  __syncthreads();
  float dot0[16], dot1[16];
#pragma unroll
  for (int k = 0; k < 16; ++k) { dot0[k] = 0.f; dot1[k] = 0.f; }
  float x20 = 0.f, x21 = 0.f;
  const unsigned short* yb = y + (size_t)b * 524288 + n0 + 2 * tid;
  for (int d4 = 0; d4 < 128; d4 += 4) {
    float xv0[4], xv1[4];
#pragma unroll
    for (int j = 0; j < 4; ++j) {
      int d = d4 + j;
      unsigned pr = *(const unsigned*)(yb + (size_t)d * 4096);
      float sc = scs[d], sh = shs[d];
      float a0 = fmaxf(fmaf(bf2f(pr & 0xFFFFu), sc, sh), 0.f);
      float a1 = fmaxf(fmaf(bf2f(pr >> 16), sc, sh), 0.f);
      xv0[j] = a0; xv1[j] = a1;
      x20 = fmaf(a0, a0, x20); x21 = fmaf(a1, a1, x21);
      *(unsigned*)&Xt[(d * 128 + 2 * tid) ^ ((d & 7) << 3)] = pk2(a0, a1);
    }
#pragma unroll
    for (int k = 0; k < 16; ++k) {
      float4 cv = *(const float4*)&cws[k][d4];
      dot0[k] += xv0[0] * cv.x + xv0[1] * cv.y + xv0[2] * cv.z + xv0[3] * cv.w;
      dot1[k] += xv1[0] * cv.x + xv1[1] * cv.y + xv1[2] * cv.z + xv1[3] * cv.w;
    }
  }
  float p0[16], p1[16];
  {
    float m0 = -1e30f, m1 = -1e30f, sl0[16], sl1[16];
#pragma unroll
    for (int k = 0; k < 16; ++k) {
      sl0[k] = sscale[k] * (x20 + c2s[k] - 2.f * dot0[k]);
      sl1[k] = sscale[k] * (x21 + c2s[k] - 2.f * dot1[k]);
      m0 = fmaxf(m0, sl0[k]); m1 = fmaxf(m1, sl1[k]);
    }
    float s0 = 0.f, s1 = 0.f;
#pragma unroll
    for (int k = 0; k < 16; ++k) {
      p0[k] = __expf(sl0[k] - m0); s0 += p0[k];
      p1[k] = __expf(sl1[k] - m1); s1 += p1[k];
    }
    float i0 = 1.f / s0, i1 = 1.f / s1;
#pragma unroll
    for (int k = 0; k < 16; ++k) { p0[k] *= i0; p1[k] *= i1; }
  }
#pragma unroll
  for (int k = 0; k < 16; ++k)
    *(unsigned*)&Pt[(k * 128 + 2 * tid) ^ ((k & 7) << 3)] = pk2(p0[k], p1[k]);
#pragma unroll
  for (int k = 0; k < 16; ++k) {
    float v = p0[k] + p1[k];
#pragma unroll
    for (int off = 32; off; off >>= 1) v += __shfl_xor(v, off);
    if (lane == 0) atomicAdd(&S0[b * 16 + k], v);
  }
  __syncthreads();
  const int li = lane & 15, q = lane >> 4;
  f32x4 eacc[4];
#pragma unroll
  for (int dt = 0; dt < 4; ++dt) eacc[dt] = (f32x4){0.f, 0.f, 0.f, 0.f};
#pragma unroll
  for (int ks = 0; ks < 4; ++ks) {
    int t0 = ks * 32 + q * 8;
    short8 af = *(const short8*)&Pt[(li * 128 + t0) ^ ((li & 7) << 3)];
#pragma unroll
    for (int dt = 0; dt < 4; ++dt) {
      int d = (wv * 4 + dt) * 16 + li;
      short8 bf = *(const short8*)&Xt[(d * 128 + t0) ^ ((d & 7) << 3)];
      eacc[dt] = __builtin_amdgcn_mfma_f32_16x16x32_bf16(af, bf, eacc[dt], 0, 0, 0);
    }
  }
  float* eb = e_acc + (size_t)b * 2048;
#pragma unroll
  for (int dt = 0; dt < 4; ++dt) {
    int d = (wv * 4 + dt) * 16 + li;
#pragma unroll
    for (int r = 0; r < 4; ++r) {
      int k = q * 4 + r;
      atomicAdd(&eb[k * 128 + d], eacc[dt][r]);
    }
  }
}

// ---------------- Phase 3 (fused gate+scale): round-8 exact (512 blocks)
__global__ __launch_bounds__(256) void gscale(const float* __restrict__ e_acc,
    const float* __restrict__ S0, const float* __restrict__ cw,
    const float* __restrict__ lin_w, const float* __restrict__ lin_b,
    const float* __restrict__ x, float* __restrict__ out) {
  const int b = blockIdx.y;
  const int cb = blockIdx.x;
  const int tid = threadIdx.x;
  __shared__ float es[2048];
  __shared__ float sred[256];
  __shared__ float s_inv;
  __shared__ float gs[16];
  const float* eb = e_acc + (size_t)b * 2048;
  float ss = 0.f;
  for (int i = tid; i < 512; i += 256) {
    float4 v = ((const float4*)eb)[i];
    int k = i >> 5;
    int dbase = (i * 4) & 127;
    float s0k = S0[b * 16 + k];
    const float4 cv = *(const float4*)(cw + k * 128 + dbase);
    v.x -= s0k * cv.x; v.y -= s0k * cv.y; v.z -= s0k * cv.z; v.w -= s0k * cv.w;
    *(float4*)&es[i * 4] = v;
    ss += v.x * v.x + v.y * v.y + v.z * v.z + v.w * v.w;
  }
  sred[tid] = ss;
  __syncthreads();
  for (int off = 128; off; off >>= 1) {
    if (tid < off) sred[tid] += sred[tid + off];
    __syncthreads();
  }
  if (tid == 0) s_inv = 1.f / fmaxf(sqrtf(sred[0]), 1e-12f);
  __syncthreads();
  const int lane = tid & 63, wid = tid >> 6;
#pragma unroll
  for (int i = 0; i < 4; ++i) {
    int ch = wid * 4 + i;
    int c = cb * 16 + ch;
    const float* wr = lin_w + (size_t)c * 2048;
    float dotv = 0.f;
#pragma unroll
    for (int j = 0; j < 8; ++j) {
      int idx = j * 64 + lane;
      float4 wv = ((const float4*)wr)[idx];
      const float* ep = &es[idx * 4];
      dotv += wv.x * ep[0] + wv.y * ep[1] + wv.z * ep[2] + wv.w * ep[3];
    }
#pragma unroll
    for (int off = 32; off; off >>= 1) dotv += __shfl_xor(dotv, off);
    if (lane == 0) {
      float z = dotv * s_inv + lin_b[c];
      gs[ch] = 1.f / (1.f + __expf(-z));
    }
  }
  __syncthreads();
  const float* xb = x + ((size_t)b * 512 + cb * 16) * 4096;
  float* ob = out + ((size_t)b * 512 + cb * 16) * 4096;
#pragma unroll 2
  for (int ch = 0; ch < 16; ++ch) {
    float g = gs[ch];
    const float4* xp = (const float4*)(xb + ch * 4096);
    float4* op = (float4*)(ob + ch * 4096);
    for (int i = tid; i < 1024; i += 256) {
      float4 v = xp[i];
      v.x *= g; v.y *= g; v.z *= g; v.w *= g;
      op[i] = v;
    }
  }
}

extern "C" void kernel_launch(void* const* d_in, const int* in_sizes, int n_in,
                              void* d_out, int out_size, void* d_ws, size_t ws_size,
                              hipStream_t stream) {
  const float* x      = (const float*)d_in[0];
  const float* conv_w = (const float*)d_in[1];
  const float* conv_b = (const float*)d_in[2];
  const float* bn_g   = (const float*)d_in[3];
  const float* bn_b   = (const float*)d_in[4];
  const float* cw     = (const float*)d_in[5];
  const float* scale  = (const float*)d_in[6];
  const float* lin_w  = (const float*)d_in[7];
  const float* lin_b  = (const float*)d_in[8];
  float* out = (float*)d_out;
  float* ws  = (float*)d_ws;

  unsigned short* y = (unsigned short*)ws;            // [0, 4194304) floats
  float* S0     = ws + 4194304;                       // 256
  float* bn_acc = ws + 4194560;                       // 256
  float* e_acc  = ws + 4194816;                       // 32768
  unsigned short* w_bf = (unsigned short*)(ws + 4227584);   // 65536 ushorts

  prep<<<64, 256, 0, stream>>>(conv_w, w_bf, S0, e_acc);
  conv_mfma<<<dim3(32, 16), 256, 0, stream>>>(x, w_bf, conv_b, y, bn_acc);
  // PROBE: encode launched 5x; S0+e_acc re-zeroed between reps so the final
  // state equals a single run. enc_t = (dur_us - 156.8 - ~10) / 4
  encode<<<dim3(32, 16), 128, 0, stream>>>(y, bn_acc, bn_g, bn_b, cw, scale, e_acc, S0);
  zero_se<<<128, 256, 0, stream>>>(S0, e_acc);
  encode<<<dim3(32, 16), 128, 0, stream>>>(y, bn_acc, bn_g, bn_b, cw, scale, e_acc, S0);
  zero_se<<<128, 256, 0, stream>>>(S0, e_acc);
  encode<<<dim3(32, 16), 128, 0, stream>>>(y, bn_acc, bn_g, bn_b, cw, scale, e_acc, S0);
  zero_se<<<128, 256, 0, stream>>>(S0, e_acc);
  encode<<<dim3(32, 16), 128, 0, stream>>>(y, bn_acc, bn_g, bn_b, cw, scale, e_acc, S0);
  zero_se<<<128, 256, 0, stream>>>(S0, e_acc);
  encode<<<dim3(32, 16), 128, 0, stream>>>(y, bn_acc, bn_g, bn_b, cw, scale, e_acc, S0);
  gscale<<<dim3(32, 16), 256, 0, stream>>>(e_acc, S0, cw, lin_w, lin_b, x, out);
}

// Round 18
// 173.863 us; speedup vs baseline: 2.3686x; 2.3686x over previous
//
#include <hip/hip_runtime.h>
#include <hip/hip_bf16.h>

typedef __attribute__((ext_vector_type(8))) short short8;
typedef __attribute__((ext_vector_type(4))) float f32x4;

#define LDW 40   // conv LDS row pitch in ushorts (80 B)

__device__ __forceinline__ unsigned short f2bf(float f) {
  __hip_bfloat16 h = __float2bfloat16(f);
  return *(unsigned short*)&h;
}
__device__ __forceinline__ float bf2f(unsigned h) {
  return __uint_as_float(h << 16);
}
__device__ __forceinline__ unsigned pk2(float a, float b) {
  return (unsigned)f2bf(a) | ((unsigned)f2bf(b) << 16);
}
__device__ __forceinline__ unsigned long long pack4(float a, float b, float c, float d) {
  return (unsigned long long)pk2(a, b) | ((unsigned long long)pk2(c, d) << 32);
}

// ---------------- prep: w -> bf16, zero S0+bn_acc+e_acc
__global__ __launch_bounds__(256) void prep(const float* __restrict__ w,
    unsigned short* __restrict__ w_bf, float* __restrict__ S0, float* __restrict__ e_acc) {
  int i = blockIdx.x * 256 + threadIdx.x;
  float4 v = ((const float4*)w)[i];
  *(unsigned long long*)(w_bf + 4 * i) = pack4(v.x, v.y, v.z, v.w);
  e_acc[2 * i] = 0.f;
  e_acc[2 * i + 1] = 0.f;
  if (blockIdx.x == 0) {
    S0[threadIdx.x] = 0.f;
    S0[256 + threadIdx.x] = 0.f;
  }
}

// ---------------- Phase 1: conv as bf16 MFMA GEMM (round-8 exact), y bf16 [b][d][n]
__global__ __launch_bounds__(256) void conv_mfma(const float* __restrict__ x,
    const unsigned short* __restrict__ w_bf, const float* __restrict__ bias,
    unsigned short* __restrict__ y, float* __restrict__ bn_acc) {
  const int b = blockIdx.y;
  const int n0 = blockIdx.x * 128;
  const int tid = threadIdx.x;
  const int lane = tid & 63, wv = tid >> 6;
  const int li = lane & 15, q = lane >> 4;
  __shared__ unsigned short Wl[128 * LDW];
  __shared__ unsigned short Xl[128 * LDW];
  f32x4 acc[2][8];
#pragma unroll
  for (int m = 0; m < 2; ++m)
#pragma unroll
    for (int r = 0; r < 8; ++r) acc[m][r] = (f32x4){0.f, 0.f, 0.f, 0.f};
  const float* xb = x + (size_t)b * (512 * 4096) + n0;
  const int nq = tid & 31, cgp = tid >> 5;
  for (int c0 = 0; c0 < 512; c0 += 32) {
#pragma unroll
    for (int i = 0; i < 2; ++i) {
      int idx = tid + i * 256;
      int d = idx >> 2, hh = idx & 3;
      *(short8*)&Wl[d * LDW + hh * 8] = *(const short8*)(w_bf + (size_t)d * 512 + c0 + hh * 8);
    }
    {
      const float* xp = xb + (size_t)(c0 + cgp * 4) * 4096 + nq * 4;
      float4 v0 = *(const float4*)(xp);
      float4 v1 = *(const float4*)(xp + 4096);
      float4 v2 = *(const float4*)(xp + 2 * 4096);
      float4 v3 = *(const float4*)(xp + 3 * 4096);
      const float* a0 = (const float*)&v0;
      const float* a1 = (const float*)&v1;
      const float* a2 = (const float*)&v2;
      const float* a3 = (const float*)&v3;
#pragma unroll
      for (int j = 0; j < 4; ++j) {
        *(unsigned long long*)&Xl[(nq * 4 + j) * LDW + cgp * 4] =
            pack4(a0[j], a1[j], a2[j], a3[j]);
      }
    }
    __syncthreads();
    short8 af[2], bfr[8];
#pragma unroll
    for (int m = 0; m < 2; ++m)
      af[m] = *(const short8*)&Xl[(32 * wv + 16 * m + li) * LDW + q * 8];
#pragma unroll
    for (int r = 0; r < 8; ++r)
      bfr[r] = *(const short8*)&Wl[(16 * r + li) * LDW + q * 8];
#pragma unroll
    for (int m = 0; m < 2; ++m)
#pragma unroll
      for (int r = 0; r < 8; ++r)
        acc[m][r] = __builtin_amdgcn_mfma_f32_16x16x32_bf16(af[m], bfr[r], acc[m][r], 0, 0, 0);
    __syncthreads();
  }
  float s1[8], s2[8];
#pragma unroll
  for (int r = 0; r < 8; ++r) { s1[r] = 0.f; s2[r] = 0.f; }
#pragma unroll
  for (int r = 0; r < 8; ++r) {
    int d = 16 * r + li;
    float bb = bias[d];
#pragma unroll
    for (int m = 0; m < 2; ++m) {
      int nl = 32 * wv + 16 * m + 4 * q;
      float v0 = acc[m][r][0] + bb, v1 = acc[m][r][1] + bb;
      float v2 = acc[m][r][2] + bb, v3 = acc[m][r][3] + bb;
      s1[r] += v0 + v1 + v2 + v3;
      s2[r] += v0 * v0 + v1 * v1 + v2 * v2 + v3 * v3;
      *(unsigned long long*)(y + ((size_t)(b * 128 + d)) * 4096 + n0 + nl) =
          pack4(v0, v1, v2, v3);
    }
  }
#pragma unroll
  for (int r = 0; r < 8; ++r) {
    s1[r] += __shfl_xor(s1[r], 16); s1[r] += __shfl_xor(s1[r], 32);
    s2[r] += __shfl_xor(s2[r], 16); s2[r] += __shfl_xor(s2[r], 32);
  }
  float* red = (float*)Wl;
  if (lane < 16) {
#pragma unroll
    for (int r = 0; r < 8; ++r) {
      red[0 * 512 + wv * 128 + r * 16 + li] = s1[r];
      red[1 * 512 + wv * 128 + r * 16 + li] = s2[r];
    }
  }
  __syncthreads();
  {
    int s = tid >> 7, d = tid & 127;
    float v = red[s * 512 + d] + red[s * 512 + 128 + d]
            + red[s * 512 + 256 + d] + red[s * 512 + 384 + d];
    atomicAdd(&bn_acc[s * 128 + d], v);
  }
}

// ---------------- Phase 2 (fused assign+aggregate), REWRITTEN:
// 256 threads, 128 tokens/block exactly once. Thread (tp,h): token pair tp,
// d-quarter [32h,32h+32). Partials combined via shfl_xor(16/32).
__global__ __launch_bounds__(256) void encode(const unsigned short* __restrict__ y,
    const float* __restrict__ bn_acc, const float* __restrict__ bn_g,
    const float* __restrict__ bn_b, const float* __restrict__ cw,
    const float* __restrict__ scale, float* __restrict__ e_acc, float* __restrict__ S0) {
  const int b = blockIdx.y;
  const int n0 = blockIdx.x * 128;
  const int tid = threadIdx.x;              // 0..255
  const int lane = tid & 63, wv = tid >> 6; // 4 waves
  const int tp = wv * 16 + (lane & 15);     // token pair 0..63 (tokens 2tp,2tp+1)
  const int h = (lane >> 4) & 3;            // d-quarter
  __shared__ unsigned short Xt[128 * 128];  // [d][tok] bf16, idx ^= (d&7)<<3
  __shared__ unsigned short Pt[16 * 128];   // [k][tok] bf16, idx ^= (k&7)<<3
  __shared__ float cws[16][128];
  __shared__ float c2s[16], scs[128], shs[128], sscale[16];
  for (int i = tid; i < 2048; i += 256) cws[i >> 7][i & 127] = cw[i];
  if (tid < 128) {
    float mu = bn_acc[tid] * (1.f / 65536.f);
    float var = bn_acc[128 + tid] * (1.f / 65536.f) - mu * mu;
    float sc = rsqrtf(var + 1e-5f) * bn_g[tid];
    scs[tid] = sc;
    shs[tid] = bn_b[tid] - mu * sc;
  }
  if (tid < 16) sscale[tid] = scale[tid];
  __syncthreads();
  if (tid < 16) {
    float s = 0.f;
#pragma unroll
    for (int d = 0; d < 128; ++d) s += cws[tid][d] * cws[tid][d];
    c2s[tid] = s;
  }
  __syncthreads();
  // partial dots over this thread's d-quarter
  float dot0[16], dot1[16];
#pragma unroll
  for (int k = 0; k < 16; ++k) { dot0[k] = 0.f; dot1[k] = 0.f; }
  float x20 = 0.f, x21 = 0.f;
  const unsigned short* yb = y + (size_t)b * 524288 + n0 + 2 * tp;
  for (int j = 0; j < 8; ++j) {
    const int d4 = 32 * h + 4 * j;
    float xv0[4], xv1[4];
#pragma unroll
    for (int jj = 0; jj < 4; ++jj) {
      int d = d4 + jj;
      unsigned pr = *(const unsigned*)(yb + (size_t)d * 4096);
      float sc = scs[d], sh = shs[d];
      float a0 = fmaxf(fmaf(bf2f(pr & 0xFFFFu), sc, sh), 0.f);
      float a1 = fmaxf(fmaf(bf2f(pr >> 16), sc, sh), 0.f);
      xv0[jj] = a0; xv1[jj] = a1;
      x20 = fmaf(a0, a0, x20); x21 = fmaf(a1, a1, x21);
      *(unsigned*)&Xt[(d * 128 + 2 * tp) ^ ((d & 7) << 3)] = pk2(a0, a1);
    }
#pragma unroll
    for (int k = 0; k < 16; ++k) {
      float4 cv = *(const float4*)&cws[k][d4];
      dot0[k] += xv0[0] * cv.x + xv0[1] * cv.y + xv0[2] * cv.z + xv0[3] * cv.w;
      dot1[k] += xv1[0] * cv.x + xv1[1] * cv.y + xv1[2] * cv.z + xv1[3] * cv.w;
    }
  }
  // combine the 4 d-quarter partials (lanes l, l+16, l+32, l+48)
#pragma unroll
  for (int k = 0; k < 16; ++k) {
    dot0[k] += __shfl_xor(dot0[k], 16); dot0[k] += __shfl_xor(dot0[k], 32);
    dot1[k] += __shfl_xor(dot1[k], 16); dot1[k] += __shfl_xor(dot1[k], 32);
  }
  x20 += __shfl_xor(x20, 16); x20 += __shfl_xor(x20, 32);
  x21 += __shfl_xor(x21, 16); x21 += __shfl_xor(x21, 32);
  // softmax (all lanes hold identical combined values; compute redundantly)
  float p0[16], p1[16];
  {
    float m0 = -1e30f, m1 = -1e30f, sl0[16], sl1[16];
#pragma unroll
    for (int k = 0; k < 16; ++k) {
      sl0[k] = sscale[k] * (x20 + c2s[k] - 2.f * dot0[k]);
      sl1[k] = sscale[k] * (x21 + c2s[k] - 2.f * dot1[k]);
      m0 = fmaxf(m0, sl0[k]); m1 = fmaxf(m1, sl1[k]);
    }
    float s0 = 0.f, s1 = 0.f;
#pragma unroll
    for (int k = 0; k < 16; ++k) {
      p0[k] = __expf(sl0[k] - m0); s0 += p0[k];
      p1[k] = __expf(sl1[k] - m1); s1 += p1[k];
    }
    float i0 = 1.f / s0, i1 = 1.f / s1;
#pragma unroll
    for (int k = 0; k < 16; ++k) { p0[k] *= i0; p1[k] *= i1; }
  }
  // Pt written once per token pair (h==0 lanes)
  if (h == 0) {
#pragma unroll
    for (int k = 0; k < 16; ++k)
      *(unsigned*)&Pt[(k * 128 + 2 * tp) ^ ((k & 7) << 3)] = pk2(p0[k], p1[k]);
  }
  // S0: exact single count — reduce over the wave's 16 pairs, add once per wave
#pragma unroll
  for (int k = 0; k < 16; ++k) {
    float v = p0[k] + p1[k];
    v += __shfl_xor(v, 1); v += __shfl_xor(v, 2);
    v += __shfl_xor(v, 4); v += __shfl_xor(v, 8);
    if (lane == 0) atomicAdd(&S0[b * 16 + k], v);
  }
  __syncthreads();
  // E[k][d] += P^T X via MFMA: 4 waves x 2 d-tiles
  const int li = lane & 15, q = lane >> 4;
  f32x4 eacc[2];
  eacc[0] = (f32x4){0.f, 0.f, 0.f, 0.f};
  eacc[1] = (f32x4){0.f, 0.f, 0.f, 0.f};
#pragma unroll
  for (int ks = 0; ks < 4; ++ks) {
    int t0 = ks * 32 + q * 8;
    short8 af = *(const short8*)&Pt[(li * 128 + t0) ^ ((li & 7) << 3)];
#pragma unroll
    for (int j = 0; j < 2; ++j) {
      int d = (wv * 2 + j) * 16 + li;
      short8 bf = *(const short8*)&Xt[(d * 128 + t0) ^ ((d & 7) << 3)];
      eacc[j] = __builtin_amdgcn_mfma_f32_16x16x32_bf16(af, bf, eacc[j], 0, 0, 0);
    }
  }
  float* eb = e_acc + (size_t)b * 2048;
#pragma unroll
  for (int j = 0; j < 2; ++j) {
    int d = (wv * 2 + j) * 16 + li;
#pragma unroll
    for (int r = 0; r < 4; ++r)
      atomicAdd(&eb[(q * 4 + r) * 128 + d], eacc[j][r]);
  }
}

// ---------------- Phase 3 (fused gate+scale): round-8 exact (512 blocks)
__global__ __launch_bounds__(256) void gscale(const float* __restrict__ e_acc,
    const float* __restrict__ S0, const float* __restrict__ cw,
    const float* __restrict__ lin_w, const float* __restrict__ lin_b,
    const float* __restrict__ x, float* __restrict__ out) {
  const int b = blockIdx.y;
  const int cb = blockIdx.x;
  const int tid = threadIdx.x;
  __shared__ float es[2048];
  __shared__ float sred[256];
  __shared__ float s_inv;
  __shared__ float gs[16];
  const float* eb = e_acc + (size_t)b * 2048;
  float ss = 0.f;
  for (int i = tid; i < 512; i += 256) {
    float4 v = ((const float4*)eb)[i];
    int k = i >> 5;
    int dbase = (i * 4) & 127;
    float s0k = S0[b * 16 + k];
    const float4 cv = *(const float4*)(cw + k * 128 + dbase);
    v.x -= s0k * cv.x; v.y -= s0k * cv.y; v.z -= s0k * cv.z; v.w -= s0k * cv.w;
    *(float4*)&es[i * 4] = v;
    ss += v.x * v.x + v.y * v.y + v.z * v.z + v.w * v.w;
  }
  sred[tid] = ss;
  __syncthreads();
  for (int off = 128; off; off >>= 1) {
    if (tid < off) sred[tid] += sred[tid + off];
    __syncthreads();
  }
  if (tid == 0) s_inv = 1.f / fmaxf(sqrtf(sred[0]), 1e-12f);
  __syncthreads();
  const int lane = tid & 63, wid = tid >> 6;
#pragma unroll
  for (int i = 0; i < 4; ++i) {
    int ch = wid * 4 + i;
    int c = cb * 16 + ch;
    const float* wr = lin_w + (size_t)c * 2048;
    float dotv = 0.f;
#pragma unroll
    for (int j = 0; j < 8; ++j) {
      int idx = j * 64 + lane;
      float4 wv = ((const float4*)wr)[idx];
      const float* ep = &es[idx * 4];
      dotv += wv.x * ep[0] + wv.y * ep[1] + wv.z * ep[2] + wv.w * ep[3];
    }
#pragma unroll
    for (int off = 32; off; off >>= 1) dotv += __shfl_xor(dotv, off);
    if (lane == 0) {
      float z = dotv * s_inv + lin_b[c];
      gs[ch] = 1.f / (1.f + __expf(-z));
    }
  }
  __syncthreads();
  const float* xb = x + ((size_t)b * 512 + cb * 16) * 4096;
  float* ob = out + ((size_t)b * 512 + cb * 16) * 4096;
#pragma unroll 2
  for (int ch = 0; ch < 16; ++ch) {
    float g = gs[ch];
    const float4* xp = (const float4*)(xb + ch * 4096);
    float4* op = (float4*)(ob + ch * 4096);
    for (int i = tid; i < 1024; i += 256) {
      float4 v = xp[i];
      v.x *= g; v.y *= g; v.z *= g; v.w *= g;
      op[i] = v;
    }
  }
}

extern "C" void kernel_launch(void* const* d_in, const int* in_sizes, int n_in,
                              void* d_out, int out_size, void* d_ws, size_t ws_size,
                              hipStream_t stream) {
  const float* x      = (const float*)d_in[0];
  const float* conv_w = (const float*)d_in[1];
  const float* conv_b = (const float*)d_in[2];
  const float* bn_g   = (const float*)d_in[3];
  const float* bn_b   = (const float*)d_in[4];
  const float* cw     = (const float*)d_in[5];
  const float* scale  = (const float*)d_in[6];
  const float* lin_w  = (const float*)d_in[7];
  const float* lin_b  = (const float*)d_in[8];
  float* out = (float*)d_out;
  float* ws  = (float*)d_ws;

  unsigned short* y = (unsigned short*)ws;            // [0, 4194304) floats
  float* S0     = ws + 4194304;                       // 256
  float* bn_acc = ws + 4194560;                       // 256
  float* e_acc  = ws + 4194816;                       // 32768
  unsigned short* w_bf = (unsigned short*)(ws + 4227584);   // 65536 ushorts

  prep<<<64, 256, 0, stream>>>(conv_w, w_bf, S0, e_acc);
  conv_mfma<<<dim3(32, 16), 256, 0, stream>>>(x, w_bf, conv_b, y, bn_acc);
  encode<<<dim3(32, 16), 256, 0, stream>>>(y, bn_acc, bn_g, bn_b, cw, scale, e_acc, S0);
  gscale<<<dim3(32, 16), 256, 0, stream>>>(e_acc, S0, cw, lin_w, lin_b, x, out);
}

// Round 19
// 117.622 us; speedup vs baseline: 3.5011x; 1.4782x over previous
//
#include <hip/hip_runtime.h>
#include <hip/hip_bf16.h>

typedef __attribute__((ext_vector_type(8))) short short8;
typedef __attribute__((ext_vector_type(4))) float f32x4;

#define LDW 40   // conv LDS row pitch in ushorts (80 B)

__device__ __forceinline__ unsigned short f2bf(float f) {
  __hip_bfloat16 h = __float2bfloat16(f);
  return *(unsigned short*)&h;
}
__device__ __forceinline__ float bf2f(unsigned h) {
  return __uint_as_float(h << 16);
}
__device__ __forceinline__ unsigned pk2(float a, float b) {
  return (unsigned)f2bf(a) | ((unsigned)f2bf(b) << 16);
}
__device__ __forceinline__ unsigned long long pack4(float a, float b, float c, float d) {
  return (unsigned long long)pk2(a, b) | ((unsigned long long)pk2(c, d) << 32);
}

// ---------------- prep: w -> bf16, zero S0+bn_acc+e_acc
__global__ __launch_bounds__(256) void prep(const float* __restrict__ w,
    unsigned short* __restrict__ w_bf, float* __restrict__ S0, float* __restrict__ e_acc) {
  int i = blockIdx.x * 256 + threadIdx.x;
  float4 v = ((const float4*)w)[i];
  *(unsigned long long*)(w_bf + 4 * i) = pack4(v.x, v.y, v.z, v.w);
  e_acc[2 * i] = 0.f;
  e_acc[2 * i + 1] = 0.f;
  if (blockIdx.x == 0) {
    S0[threadIdx.x] = 0.f;
    S0[256 + threadIdx.x] = 0.f;
  }
}

// ---------------- Phase 1: conv as bf16 MFMA GEMM (round-8 exact), y bf16 [b][d][n]
__global__ __launch_bounds__(256) void conv_mfma(const float* __restrict__ x,
    const unsigned short* __restrict__ w_bf, const float* __restrict__ bias,
    unsigned short* __restrict__ y, float* __restrict__ bn_acc) {
  const int b = blockIdx.y;
  const int n0 = blockIdx.x * 128;
  const int tid = threadIdx.x;
  const int lane = tid & 63, wv = tid >> 6;
  const int li = lane & 15, q = lane >> 4;
  __shared__ unsigned short Wl[128 * LDW];
  __shared__ unsigned short Xl[128 * LDW];
  f32x4 acc[2][8];
#pragma unroll
  for (int m = 0; m < 2; ++m)
#pragma unroll
    for (int r = 0; r < 8; ++r) acc[m][r] = (f32x4){0.f, 0.f, 0.f, 0.f};
  const float* xb = x + (size_t)b * (512 * 4096) + n0;
  const int nq = tid & 31, cgp = tid >> 5;
  for (int c0 = 0; c0 < 512; c0 += 32) {
#pragma unroll
    for (int i = 0; i < 2; ++i) {
      int idx = tid + i * 256;
      int d = idx >> 2, hh = idx & 3;
      *(short8*)&Wl[d * LDW + hh * 8] = *(const short8*)(w_bf + (size_t)d * 512 + c0 + hh * 8);
    }
    {
      const float* xp = xb + (size_t)(c0 + cgp * 4) * 4096 + nq * 4;
      float4 v0 = *(const float4*)(xp);
      float4 v1 = *(const float4*)(xp + 4096);
      float4 v2 = *(const float4*)(xp + 2 * 4096);
      float4 v3 = *(const float4*)(xp + 3 * 4096);
      const float* a0 = (const float*)&v0;
      const float* a1 = (const float*)&v1;
      const float* a2 = (const float*)&v2;
      const float* a3 = (const float*)&v3;
#pragma unroll
      for (int j = 0; j < 4; ++j) {
        *(unsigned long long*)&Xl[(nq * 4 + j) * LDW + cgp * 4] =
            pack4(a0[j], a1[j], a2[j], a3[j]);
      }
    }
    __syncthreads();
    short8 af[2], bfr[8];
#pragma unroll
    for (int m = 0; m < 2; ++m)
      af[m] = *(const short8*)&Xl[(32 * wv + 16 * m + li) * LDW + q * 8];
#pragma unroll
    for (int r = 0; r < 8; ++r)
      bfr[r] = *(const short8*)&Wl[(16 * r + li) * LDW + q * 8];
#pragma unroll
    for (int m = 0; m < 2; ++m)
#pragma unroll
      for (int r = 0; r < 8; ++r)
        acc[m][r] = __builtin_amdgcn_mfma_f32_16x16x32_bf16(af[m], bfr[r], acc[m][r], 0, 0, 0);
    __syncthreads();
  }
  float s1[8], s2[8];
#pragma unroll
  for (int r = 0; r < 8; ++r) { s1[r] = 0.f; s2[r] = 0.f; }
#pragma unroll
  for (int r = 0; r < 8; ++r) {
    int d = 16 * r + li;
    float bb = bias[d];
#pragma unroll
    for (int m = 0; m < 2; ++m) {
      int nl = 32 * wv + 16 * m + 4 * q;
      float v0 = acc[m][r][0] + bb, v1 = acc[m][r][1] + bb;
      float v2 = acc[m][r][2] + bb, v3 = acc[m][r][3] + bb;
      s1[r] += v0 + v1 + v2 + v3;
      s2[r] += v0 * v0 + v1 * v1 + v2 * v2 + v3 * v3;
      *(unsigned long long*)(y + ((size_t)(b * 128 + d)) * 4096 + n0 + nl) =
          pack4(v0, v1, v2, v3);
    }
  }
#pragma unroll
  for (int r = 0; r < 8; ++r) {
    s1[r] += __shfl_xor(s1[r], 16); s1[r] += __shfl_xor(s1[r], 32);
    s2[r] += __shfl_xor(s2[r], 16); s2[r] += __shfl_xor(s2[r], 32);
  }
  float* red = (float*)Wl;
  if (lane < 16) {
#pragma unroll
    for (int r = 0; r < 8; ++r) {
      red[0 * 512 + wv * 128 + r * 16 + li] = s1[r];
      red[1 * 512 + wv * 128 + r * 16 + li] = s2[r];
    }
  }
  __syncthreads();
  {
    int s = tid >> 7, d = tid & 127;
    float v = red[s * 512 + d] + red[s * 512 + 128 + d]
            + red[s * 512 + 256 + d] + red[s * 512 + 384 + d];
    atomicAdd(&bn_acc[s * 128 + d], v);
  }
}

// ---------------- Phase 2 (fused assign+aggregate) v3: dots AND E on MFMA.
// 256 threads, 128 tokens/block. XU is time-shared: X[n][d] for the S-step,
// then rewritten (from registers) as X^T[d][n] for the E-step.
__global__ __launch_bounds__(256) void encode(const unsigned short* __restrict__ y,
    const float* __restrict__ bn_acc, const float* __restrict__ bn_g,
    const float* __restrict__ bn_b, const float* __restrict__ cw,
    const float* __restrict__ scale, float* __restrict__ e_acc, float* __restrict__ S0) {
  const int b = blockIdx.y;
  const int n0 = blockIdx.x * 128;
  const int tid = threadIdx.x;
  const int lane = tid & 63, wv = tid >> 6;
  const int li = lane & 15, q = lane >> 4;
  const int tp = wv * 16 + li;         // token pair 0..63 (tokens 2tp, 2tp+1)
  __shared__ unsigned short XU[128 * 128];   // phase S: [n][d]; phase E: [d][n]
  __shared__ unsigned short Pt[16 * 128];    // [k][n], idx ^= (k&7)<<3
  __shared__ unsigned short Ct[16 * 128];    // [k][d], idx ^= (k&7)<<3
  __shared__ float scs[128], shs[128], x2s[128], c2s[16], sscale[16];

  // stage codewords bf16 (swizzled), BN fold, scale
  for (int i = tid; i < 2048; i += 256) {
    int k = i >> 7, d = i & 127;
    Ct[(k * 128 + d) ^ ((k & 7) << 3)] = f2bf(cw[i]);
  }
  if (tid < 128) {
    float mu = bn_acc[tid] * (1.f / 65536.f);
    float var = bn_acc[128 + tid] * (1.f / 65536.f) - mu * mu;
    float sc = rsqrtf(var + 1e-5f) * bn_g[tid];
    scs[tid] = sc;
    shs[tid] = bn_b[tid] - mu * sc;
  }
  if (tid < 16) sscale[tid] = scale[tid];
  __syncthreads();
  if (tid < 16) {
    float s = 0.f;
#pragma unroll 8
    for (int d = 0; d < 128; ++d) {
      float v = bf2f(Ct[(tid * 128 + d) ^ ((tid & 7) << 3)]);
      s = fmaf(v, v, s);
    }
    c2s[tid] = s;
  }
  // load y (d-quarter per thread), BN+ReLU; write X[n][d]; keep packed regs
  const int nt0 = 2 * tp, nt1 = 2 * tp + 1;
  unsigned pkv[32];
  float x20 = 0.f, x21 = 0.f;
  const unsigned short* yb = y + (size_t)b * 524288 + n0 + nt0;
#pragma unroll
  for (int j = 0; j < 8; ++j) {
    const int d4 = 32 * q + 4 * j;
    float xv0[4], xv1[4];
#pragma unroll
    for (int jj = 0; jj < 4; ++jj) {
      int d = d4 + jj;
      unsigned pr = *(const unsigned*)(yb + (size_t)d * 4096);
      float sc = scs[d], sh = shs[d];
      float a0 = fmaxf(fmaf(bf2f(pr & 0xFFFFu), sc, sh), 0.f);
      float a1 = fmaxf(fmaf(bf2f(pr >> 16), sc, sh), 0.f);
      xv0[jj] = a0; xv1[jj] = a1;
      x20 = fmaf(a0, a0, x20); x21 = fmaf(a1, a1, x21);
      pkv[j * 4 + jj] = pk2(a0, a1);
    }
    *(unsigned long long*)&XU[nt0 * 128 + (d4 ^ ((nt0 & 7) << 3))] =
        pack4(xv0[0], xv0[1], xv0[2], xv0[3]);
    *(unsigned long long*)&XU[nt1 * 128 + (d4 ^ ((nt1 & 7) << 3))] =
        pack4(xv1[0], xv1[1], xv1[2], xv1[3]);
  }
  x20 += __shfl_xor(x20, 16); x20 += __shfl_xor(x20, 32);
  x21 += __shfl_xor(x21, 16); x21 += __shfl_xor(x21, 32);
  if (q == 0) { x2s[nt0] = x20; x2s[nt1] = x21; }
  __syncthreads();

  // S-step: dot[k][n] via MFMA; softmax per token; Pt + exact S0
  short8 cf[4];
#pragma unroll
  for (int ks = 0; ks < 4; ++ks)
    cf[ks] = *(const short8*)&Ct[(li * 128 + ks * 32 + q * 8) ^ ((li & 7) << 3)];
  float s0a[4] = {0.f, 0.f, 0.f, 0.f};
#pragma unroll
  for (int ti = 0; ti < 2; ++ti) {
    const int t = wv * 2 + ti;           // token tile 0..7
    const int n = t * 16 + li;           // this lane's token (load row == output col)
    f32x4 sacc = (f32x4){0.f, 0.f, 0.f, 0.f};
#pragma unroll
    for (int ks = 0; ks < 4; ++ks) {
      short8 xf = *(const short8*)&XU[(n * 128 + ks * 32 + q * 8) ^ ((n & 7) << 3)];
      sacc = __builtin_amdgcn_mfma_f32_16x16x32_bf16(cf[ks], xf, sacc, 0, 0, 0);
    }
    float x2n = x2s[n];
    float sl[4], m = -1e30f;
#pragma unroll
    for (int r = 0; r < 4; ++r) {
      int k = 4 * q + r;
      sl[r] = sscale[k] * (x2n + c2s[k] - 2.f * sacc[r]);
      m = fmaxf(m, sl[r]);
    }
    m = fmaxf(m, __shfl_xor(m, 16));
    m = fmaxf(m, __shfl_xor(m, 32));
    float e[4], s = 0.f;
#pragma unroll
    for (int r = 0; r < 4; ++r) { e[r] = __expf(sl[r] - m); s += e[r]; }
    s += __shfl_xor(s, 16);
    s += __shfl_xor(s, 32);
    float inv = 1.f / s;
#pragma unroll
    for (int r = 0; r < 4; ++r) {
      float p = e[r] * inv;
      int k = 4 * q + r;
      Pt[(k * 128 + n) ^ ((k & 7) << 3)] = f2bf(p);
      s0a[r] += p;
    }
  }
#pragma unroll
  for (int r = 0; r < 4; ++r) {
    float v = s0a[r];
    v += __shfl_xor(v, 1); v += __shfl_xor(v, 2);
    v += __shfl_xor(v, 4); v += __shfl_xor(v, 8);
    if (li == 0) atomicAdd(&S0[b * 16 + 4 * q + r], v);
  }
  __syncthreads();

  // rewrite register copy as X^T[d][n] (overwrites the [n][d] view)
#pragma unroll
  for (int j = 0; j < 8; ++j) {
#pragma unroll
    for (int jj = 0; jj < 4; ++jj) {
      int d = 32 * q + 4 * j + jj;
      *(unsigned*)&XU[(d * 128 + nt0) ^ ((d & 7) << 3)] = pkv[j * 4 + jj];
    }
  }
  __syncthreads();

  // E-step: E[k][d] += P^T X via MFMA (4 waves x 2 d-tiles)
  f32x4 eacc[2];
  eacc[0] = (f32x4){0.f, 0.f, 0.f, 0.f};
  eacc[1] = (f32x4){0.f, 0.f, 0.f, 0.f};
#pragma unroll
  for (int ks = 0; ks < 4; ++ks) {
    int t0 = ks * 32 + q * 8;
    short8 af = *(const short8*)&Pt[(li * 128 + t0) ^ ((li & 7) << 3)];
#pragma unroll
    for (int j = 0; j < 2; ++j) {
      int d = (wv * 2 + j) * 16 + li;
      short8 bf = *(const short8*)&XU[(d * 128 + t0) ^ ((d & 7) << 3)];
      eacc[j] = __builtin_amdgcn_mfma_f32_16x16x32_bf16(af, bf, eacc[j], 0, 0, 0);
    }
  }
  float* eb = e_acc + (size_t)b * 2048;
#pragma unroll
  for (int j = 0; j < 2; ++j) {
    int d = (wv * 2 + j) * 16 + li;
#pragma unroll
    for (int r = 0; r < 4; ++r)
      atomicAdd(&eb[(q * 4 + r) * 128 + d], eacc[j][r]);
  }
}

// ---------------- Phase 3 (fused gate+scale): round-8 exact (512 blocks)
__global__ __launch_bounds__(256) void gscale(const float* __restrict__ e_acc,
    const float* __restrict__ S0, const float* __restrict__ cw,
    const float* __restrict__ lin_w, const float* __restrict__ lin_b,
    const float* __restrict__ x, float* __restrict__ out) {
  const int b = blockIdx.y;
  const int cb = blockIdx.x;
  const int tid = threadIdx.x;
  __shared__ float es[2048];
  __shared__ float sred[256];
  __shared__ float s_inv;
  __shared__ float gs[16];
  const float* eb = e_acc + (size_t)b * 2048;
  float ss = 0.f;
  for (int i = tid; i < 512; i += 256) {
    float4 v = ((const float4*)eb)[i];
    int k = i >> 5;
    int dbase = (i * 4) & 127;
    float s0k = S0[b * 16 + k];
    const float4 cv = *(const float4*)(cw + k * 128 + dbase);
    v.x -= s0k * cv.x; v.y -= s0k * cv.y; v.z -= s0k * cv.z; v.w -= s0k * cv.w;
    *(float4*)&es[i * 4] = v;
    ss += v.x * v.x + v.y * v.y + v.z * v.z + v.w * v.w;
  }
  sred[tid] = ss;
  __syncthreads();
  for (int off = 128; off; off >>= 1) {
    if (tid < off) sred[tid] += sred[tid + off];
    __syncthreads();
  }
  if (tid == 0) s_inv = 1.f / fmaxf(sqrtf(sred[0]), 1e-12f);
  __syncthreads();
  const int lane = tid & 63, wid = tid >> 6;
#pragma unroll
  for (int i = 0; i < 4; ++i) {
    int ch = wid * 4 + i;
    int c = cb * 16 + ch;
    const float* wr = lin_w + (size_t)c * 2048;
    float dotv = 0.f;
#pragma unroll
    for (int j = 0; j < 8; ++j) {
      int idx = j * 64 + lane;
      float4 wv = ((const float4*)wr)[idx];
      const float* ep = &es[idx * 4];
      dotv += wv.x * ep[0] + wv.y * ep[1] + wv.z * ep[2] + wv.w * ep[3];
    }
#pragma unroll
    for (int off = 32; off; off >>= 1) dotv += __shfl_xor(dotv, off);
    if (lane == 0) {
      float z = dotv * s_inv + lin_b[c];
      gs[ch] = 1.f / (1.f + __expf(-z));
    }
  }
  __syncthreads();
  const float* xb = x + ((size_t)b * 512 + cb * 16) * 4096;
  float* ob = out + ((size_t)b * 512 + cb * 16) * 4096;
#pragma unroll 2
  for (int ch = 0; ch < 16; ++ch) {
    float g = gs[ch];
    const float4* xp = (const float4*)(xb + ch * 4096);
    float4* op = (float4*)(ob + ch * 4096);
    for (int i = tid; i < 1024; i += 256) {
      float4 v = xp[i];
      v.x *= g; v.y *= g; v.z *= g; v.w *= g;
      op[i] = v;
    }
  }
}

extern "C" void kernel_launch(void* const* d_in, const int* in_sizes, int n_in,
                              void* d_out, int out_size, void* d_ws, size_t ws_size,
                              hipStream_t stream) {
  const float* x      = (const float*)d_in[0];
  const float* conv_w = (const float*)d_in[1];
  const float* conv_b = (const float*)d_in[2];
  const float* bn_g   = (const float*)d_in[3];
  const float* bn_b   = (const float*)d_in[4];
  const float* cw     = (const float*)d_in[5];
  const float* scale  = (const float*)d_in[6];
  const float* lin_w  = (const float*)d_in[7];
  const float* lin_b  = (const float*)d_in[8];
  float* out = (float*)d_out;
  float* ws  = (float*)d_ws;

  unsigned short* y = (unsigned short*)ws;            // [0, 4194304) floats
  float* S0     = ws + 4194304;                       // 256
  float* bn_acc = ws + 4194560;                       // 256
  float* e_acc  = ws + 4194816;                       // 32768
  unsigned short* w_bf = (unsigned short*)(ws + 4227584);   // 65536 ushorts

  prep<<<64, 256, 0, stream>>>(conv_w, w_bf, S0, e_acc);
  conv_mfma<<<dim3(32, 16), 256, 0, stream>>>(x, w_bf, conv_b, y, bn_acc);
  encode<<<dim3(32, 16), 256, 0, stream>>>(y, bn_acc, bn_g, bn_b, cw, scale, e_acc, S0);
  gscale<<<dim3(32, 16), 256, 0, stream>>>(e_acc, S0, cw, lin_w, lin_b, x, out);
}

// Round 20
// 114.892 us; speedup vs baseline: 3.5843x; 1.0238x over previous
//
#include <hip/hip_runtime.h>
#include <hip/hip_bf16.h>

typedef __attribute__((ext_vector_type(8))) short short8;
typedef __attribute__((ext_vector_type(4))) float f32x4;

#define LDW 40   // conv LDS row pitch in ushorts (80 B)

__device__ __forceinline__ unsigned short f2bf(float f) {
  __hip_bfloat16 h = __float2bfloat16(f);
  return *(unsigned short*)&h;
}
__device__ __forceinline__ float bf2f(unsigned h) {
  return __uint_as_float(h << 16);
}
__device__ __forceinline__ unsigned pk2(float a, float b) {
  return (unsigned)f2bf(a) | ((unsigned)f2bf(b) << 16);
}
__device__ __forceinline__ unsigned long long pack4(float a, float b, float c, float d) {
  return (unsigned long long)pk2(a, b) | ((unsigned long long)pk2(c, d) << 32);
}

// ---------------- prep: w -> bf16, zero S0+bn_acc+e_acc
__global__ __launch_bounds__(256) void prep(const float* __restrict__ w,
    unsigned short* __restrict__ w_bf, float* __restrict__ S0, float* __restrict__ e_acc) {
  int i = blockIdx.x * 256 + threadIdx.x;
  float4 v = ((const float4*)w)[i];
  *(unsigned long long*)(w_bf + 4 * i) = pack4(v.x, v.y, v.z, v.w);
  e_acc[2 * i] = 0.f;
  e_acc[2 * i + 1] = 0.f;
  if (blockIdx.x == 0) {
    S0[threadIdx.x] = 0.f;
    S0[256 + threadIdx.x] = 0.f;
  }
}

// ---------------- Phase 1: conv bf16 MFMA with software-pipelined staging:
// K-step k+1's global loads are issued before the barrier, so their latency
// hides under K-step k's MFMA phase (T14 issue-early/write-late).
__global__ __launch_bounds__(256) void conv_mfma(const float* __restrict__ x,
    const unsigned short* __restrict__ w_bf, const float* __restrict__ bias,
    unsigned short* __restrict__ y, float* __restrict__ bn_acc) {
  const int b = blockIdx.y;
  const int n0 = blockIdx.x * 128;
  const int tid = threadIdx.x;
  const int lane = tid & 63, wv = tid >> 6;
  const int li = lane & 15, q = lane >> 4;
  __shared__ unsigned short Wl[128 * LDW];
  __shared__ unsigned short Xl[128 * LDW];
  f32x4 acc[2][8];
#pragma unroll
  for (int m = 0; m < 2; ++m)
#pragma unroll
    for (int r = 0; r < 8; ++r) acc[m][r] = (f32x4){0.f, 0.f, 0.f, 0.f};
  const float* xb = x + (size_t)b * (512 * 4096) + n0;
  const int nq = tid & 31, cgp = tid >> 5;
  const int wd0 = tid >> 2, wh0 = (tid & 3) * 8;          // W chunk 0
  const int wd1 = (tid + 256) >> 2, wh1 = wh0;            // W chunk 1 (d+64)
  const float* xp0 = xb + (size_t)(cgp * 4) * 4096 + nq * 4;
  // prologue: load K-step 0 into registers
  short8 w0 = *(const short8*)(w_bf + (size_t)wd0 * 512 + wh0);
  short8 w1 = *(const short8*)(w_bf + (size_t)wd1 * 512 + wh1);
  float4 v0 = *(const float4*)(xp0);
  float4 v1 = *(const float4*)(xp0 + 4096);
  float4 v2 = *(const float4*)(xp0 + 2 * 4096);
  float4 v3 = *(const float4*)(xp0 + 3 * 4096);
  for (int c0 = 0; c0 < 512; c0 += 32) {
    // write LDS from registers
    *(short8*)&Wl[wd0 * LDW + wh0] = w0;
    *(short8*)&Wl[wd1 * LDW + wh1] = w1;
    {
      const float* a0 = (const float*)&v0;
      const float* a1 = (const float*)&v1;
      const float* a2 = (const float*)&v2;
      const float* a3 = (const float*)&v3;
#pragma unroll
      for (int j = 0; j < 4; ++j) {
        *(unsigned long long*)&Xl[(nq * 4 + j) * LDW + cgp * 4] =
            pack4(a0[j], a1[j], a2[j], a3[j]);
      }
    }
    // issue next K-step's loads (latency hides under the MFMA phase below)
    if (c0 < 480) {
      const float* xp = xp0 + (size_t)(c0 + 32) * 4096;
      w0 = *(const short8*)(w_bf + (size_t)wd0 * 512 + c0 + 32 + wh0);
      w1 = *(const short8*)(w_bf + (size_t)wd1 * 512 + c0 + 32 + wh1);
      v0 = *(const float4*)(xp);
      v1 = *(const float4*)(xp + 4096);
      v2 = *(const float4*)(xp + 2 * 4096);
      v3 = *(const float4*)(xp + 3 * 4096);
    }
    __syncthreads();
    short8 af[2], bfr[8];
#pragma unroll
    for (int m = 0; m < 2; ++m)
      af[m] = *(const short8*)&Xl[(32 * wv + 16 * m + li) * LDW + q * 8];
#pragma unroll
    for (int r = 0; r < 8; ++r)
      bfr[r] = *(const short8*)&Wl[(16 * r + li) * LDW + q * 8];
#pragma unroll
    for (int m = 0; m < 2; ++m)
#pragma unroll
      for (int r = 0; r < 8; ++r)
        acc[m][r] = __builtin_amdgcn_mfma_f32_16x16x32_bf16(af[m], bfr[r], acc[m][r], 0, 0, 0);
    __syncthreads();
  }
  float s1[8], s2[8];
#pragma unroll
  for (int r = 0; r < 8; ++r) { s1[r] = 0.f; s2[r] = 0.f; }
#pragma unroll
  for (int r = 0; r < 8; ++r) {
    int d = 16 * r + li;
    float bb = bias[d];
#pragma unroll
    for (int m = 0; m < 2; ++m) {
      int nl = 32 * wv + 16 * m + 4 * q;
      float v0e = acc[m][r][0] + bb, v1e = acc[m][r][1] + bb;
      float v2e = acc[m][r][2] + bb, v3e = acc[m][r][3] + bb;
      s1[r] += v0e + v1e + v2e + v3e;
      s2[r] += v0e * v0e + v1e * v1e + v2e * v2e + v3e * v3e;
      *(unsigned long long*)(y + ((size_t)(b * 128 + d)) * 4096 + n0 + nl) =
          pack4(v0e, v1e, v2e, v3e);
    }
  }
#pragma unroll
  for (int r = 0; r < 8; ++r) {
    s1[r] += __shfl_xor(s1[r], 16); s1[r] += __shfl_xor(s1[r], 32);
    s2[r] += __shfl_xor(s2[r], 16); s2[r] += __shfl_xor(s2[r], 32);
  }
  float* red = (float*)Wl;
  if (lane < 16) {
#pragma unroll
    for (int r = 0; r < 8; ++r) {
      red[0 * 512 + wv * 128 + r * 16 + li] = s1[r];
      red[1 * 512 + wv * 128 + r * 16 + li] = s2[r];
    }
  }
  __syncthreads();
  {
    int s = tid >> 7, d = tid & 127;
    float v = red[s * 512 + d] + red[s * 512 + 128 + d]
            + red[s * 512 + 256 + d] + red[s * 512 + 384 + d];
    atomicAdd(&bn_acc[s * 128 + d], v);
  }
}

// ---------------- Phase 2 (fused assign+aggregate) v3: dots AND E on MFMA.
__global__ __launch_bounds__(256) void encode(const unsigned short* __restrict__ y,
    const float* __restrict__ bn_acc, const float* __restrict__ bn_g,
    const float* __restrict__ bn_b, const float* __restrict__ cw,
    const float* __restrict__ scale, float* __restrict__ e_acc, float* __restrict__ S0) {
  const int b = blockIdx.y;
  const int n0 = blockIdx.x * 128;
  const int tid = threadIdx.x;
  const int lane = tid & 63, wv = tid >> 6;
  const int li = lane & 15, q = lane >> 4;
  const int tp = wv * 16 + li;         // token pair 0..63 (tokens 2tp, 2tp+1)
  __shared__ unsigned short XU[128 * 128];   // phase S: [n][d]; phase E: [d][n]
  __shared__ unsigned short Pt[16 * 128];    // [k][n], idx ^= (k&7)<<3
  __shared__ unsigned short Ct[16 * 128];    // [k][d], idx ^= (k&7)<<3
  __shared__ float scs[128], shs[128], x2s[128], c2s[16], sscale[16];

  for (int i = tid; i < 2048; i += 256) {
    int k = i >> 7, d = i & 127;
    Ct[(k * 128 + d) ^ ((k & 7) << 3)] = f2bf(cw[i]);
  }
  if (tid < 128) {
    float mu = bn_acc[tid] * (1.f / 65536.f);
    float var = bn_acc[128 + tid] * (1.f / 65536.f) - mu * mu;
    float sc = rsqrtf(var + 1e-5f) * bn_g[tid];
    scs[tid] = sc;
    shs[tid] = bn_b[tid] - mu * sc;
  }
  if (tid < 16) sscale[tid] = scale[tid];
  __syncthreads();
  if (tid < 16) {
    float s = 0.f;
#pragma unroll 8
    for (int d = 0; d < 128; ++d) {
      float v = bf2f(Ct[(tid * 128 + d) ^ ((tid & 7) << 3)]);
      s = fmaf(v, v, s);
    }
    c2s[tid] = s;
  }
  const int nt0 = 2 * tp, nt1 = 2 * tp + 1;
  unsigned pkv[32];
  float x20 = 0.f, x21 = 0.f;
  const unsigned short* yb = y + (size_t)b * 524288 + n0 + nt0;
#pragma unroll
  for (int j = 0; j < 8; ++j) {
    const int d4 = 32 * q + 4 * j;
    float xv0[4], xv1[4];
#pragma unroll
    for (int jj = 0; jj < 4; ++jj) {
      int d = d4 + jj;
      unsigned pr = *(const unsigned*)(yb + (size_t)d * 4096);
      float sc = scs[d], sh = shs[d];
      float a0 = fmaxf(fmaf(bf2f(pr & 0xFFFFu), sc, sh), 0.f);
      float a1 = fmaxf(fmaf(bf2f(pr >> 16), sc, sh), 0.f);
      xv0[jj] = a0; xv1[jj] = a1;
      x20 = fmaf(a0, a0, x20); x21 = fmaf(a1, a1, x21);
      pkv[j * 4 + jj] = pk2(a0, a1);
    }
    *(unsigned long long*)&XU[nt0 * 128 + (d4 ^ ((nt0 & 7) << 3))] =
        pack4(xv0[0], xv0[1], xv0[2], xv0[3]);
    *(unsigned long long*)&XU[nt1 * 128 + (d4 ^ ((nt1 & 7) << 3))] =
        pack4(xv1[0], xv1[1], xv1[2], xv1[3]);
  }
  x20 += __shfl_xor(x20, 16); x20 += __shfl_xor(x20, 32);
  x21 += __shfl_xor(x21, 16); x21 += __shfl_xor(x21, 32);
  if (q == 0) { x2s[nt0] = x20; x2s[nt1] = x21; }
  __syncthreads();

  short8 cf[4];
#pragma unroll
  for (int ks = 0; ks < 4; ++ks)
    cf[ks] = *(const short8*)&Ct[(li * 128 + ks * 32 + q * 8) ^ ((li & 7) << 3)];
  float s0a[4] = {0.f, 0.f, 0.f, 0.f};
#pragma unroll
  for (int ti = 0; ti < 2; ++ti) {
    const int t = wv * 2 + ti;
    const int n = t * 16 + li;
    f32x4 sacc = (f32x4){0.f, 0.f, 0.f, 0.f};
#pragma unroll
    for (int ks = 0; ks < 4; ++ks) {
      short8 xf = *(const short8*)&XU[(n * 128 + ks * 32 + q * 8) ^ ((n & 7) << 3)];
      sacc = __builtin_amdgcn_mfma_f32_16x16x32_bf16(cf[ks], xf, sacc, 0, 0, 0);
    }
    float x2n = x2s[n];
    float sl[4], m = -1e30f;
#pragma unroll
    for (int r = 0; r < 4; ++r) {
      int k = 4 * q + r;
      sl[r] = sscale[k] * (x2n + c2s[k] - 2.f * sacc[r]);
      m = fmaxf(m, sl[r]);
    }
    m = fmaxf(m, __shfl_xor(m, 16));
    m = fmaxf(m, __shfl_xor(m, 32));
    float e[4], s = 0.f;
#pragma unroll
    for (int r = 0; r < 4; ++r) { e[r] = __expf(sl[r] - m); s += e[r]; }
    s += __shfl_xor(s, 16);
    s += __shfl_xor(s, 32);
    float inv = 1.f / s;
#pragma unroll
    for (int r = 0; r < 4; ++r) {
      float p = e[r] * inv;
      int k = 4 * q + r;
      Pt[(k * 128 + n) ^ ((k & 7) << 3)] = f2bf(p);
      s0a[r] += p;
    }
  }
#pragma unroll
  for (int r = 0; r < 4; ++r) {
    float v = s0a[r];
    v += __shfl_xor(v, 1); v += __shfl_xor(v, 2);
    v += __shfl_xor(v, 4); v += __shfl_xor(v, 8);
    if (li == 0) atomicAdd(&S0[b * 16 + 4 * q + r], v);
  }
  __syncthreads();

#pragma unroll
  for (int j = 0; j < 8; ++j) {
#pragma unroll
    for (int jj = 0; jj < 4; ++jj) {
      int d = 32 * q + 4 * j + jj;
      *(unsigned*)&XU[(d * 128 + nt0) ^ ((d & 7) << 3)] = pkv[j * 4 + jj];
    }
  }
  __syncthreads();

  f32x4 eacc[2];
  eacc[0] = (f32x4){0.f, 0.f, 0.f, 0.f};
  eacc[1] = (f32x4){0.f, 0.f, 0.f, 0.f};
#pragma unroll
  for (int ks = 0; ks < 4; ++ks) {
    int t0 = ks * 32 + q * 8;
    short8 af = *(const short8*)&Pt[(li * 128 + t0) ^ ((li & 7) << 3)];
#pragma unroll
    for (int j = 0; j < 2; ++j) {
      int d = (wv * 2 + j) * 16 + li;
      short8 bf = *(const short8*)&XU[(d * 128 + t0) ^ ((d & 7) << 3)];
      eacc[j] = __builtin_amdgcn_mfma_f32_16x16x32_bf16(af, bf, eacc[j], 0, 0, 0);
    }
  }
  float* eb = e_acc + (size_t)b * 2048;
#pragma unroll
  for (int j = 0; j < 2; ++j) {
    int d = (wv * 2 + j) * 16 + li;
#pragma unroll
    for (int r = 0; r < 4; ++r)
      atomicAdd(&eb[(q * 4 + r) * 128 + d], eacc[j][r]);
  }
}

// ---------------- Phase 3 (fused gate+scale): round-8 exact (512 blocks)
__global__ __launch_bounds__(256) void gscale(const float* __restrict__ e_acc,
    const float* __restrict__ S0, const float* __restrict__ cw,
    const float* __restrict__ lin_w, const float* __restrict__ lin_b,
    const float* __restrict__ x, float* __restrict__ out) {
  const int b = blockIdx.y;
  const int cb = blockIdx.x;
  const int tid = threadIdx.x;
  __shared__ float es[2048];
  __shared__ float sred[256];
  __shared__ float s_inv;
  __shared__ float gs[16];
  const float* eb = e_acc + (size_t)b * 2048;
  float ss = 0.f;
  for (int i = tid; i < 512; i += 256) {
    float4 v = ((const float4*)eb)[i];
    int k = i >> 5;
    int dbase = (i * 4) & 127;
    float s0k = S0[b * 16 + k];
    const float4 cv = *(const float4*)(cw + k * 128 + dbase);
    v.x -= s0k * cv.x; v.y -= s0k * cv.y; v.z -= s0k * cv.z; v.w -= s0k * cv.w;
    *(float4*)&es[i * 4] = v;
    ss += v.x * v.x + v.y * v.y + v.z * v.z + v.w * v.w;
  }
  sred[tid] = ss;
  __syncthreads();
  for (int off = 128; off; off >>= 1) {
    if (tid < off) sred[tid] += sred[tid + off];
    __syncthreads();
  }
  if (tid == 0) s_inv = 1.f / fmaxf(sqrtf(sred[0]), 1e-12f);
  __syncthreads();
  const int lane = tid & 63, wid = tid >> 6;
#pragma unroll
  for (int i = 0; i < 4; ++i) {
    int ch = wid * 4 + i;
    int c = cb * 16 + ch;
    const float* wr = lin_w + (size_t)c * 2048;
    float dotv = 0.f;
#pragma unroll
    for (int j = 0; j < 8; ++j) {
      int idx = j * 64 + lane;
      float4 wv = ((const float4*)wr)[idx];
      const float* ep = &es[idx * 4];
      dotv += wv.x * ep[0] + wv.y * ep[1] + wv.z * ep[2] + wv.w * ep[3];
    }
#pragma unroll
    for (int off = 32; off; off >>= 1) dotv += __shfl_xor(dotv, off);
    if (lane == 0) {
      float z = dotv * s_inv + lin_b[c];
      gs[ch] = 1.f / (1.f + __expf(-z));
    }
  }
  __syncthreads();
  const float* xb = x + ((size_t)b * 512 + cb * 16) * 4096;
  float* ob = out + ((size_t)b * 512 + cb * 16) * 4096;
#pragma unroll 2
  for (int ch = 0; ch < 16; ++ch) {
    float g = gs[ch];
    const float4* xp = (const float4*)(xb + ch * 4096);
    float4* op = (float4*)(ob + ch * 4096);
    for (int i = tid; i < 1024; i += 256) {
      float4 v = xp[i];
      v.x *= g; v.y *= g; v.z *= g; v.w *= g;
      op[i] = v;
    }
  }
}

extern "C" void kernel_launch(void* const* d_in, const int* in_sizes, int n_in,
                              void* d_out, int out_size, void* d_ws, size_t ws_size,
                              hipStream_t stream) {
  const float* x      = (const float*)d_in[0];
  const float* conv_w = (const float*)d_in[1];
  const float* conv_b = (const float*)d_in[2];
  const float* bn_g   = (const float*)d_in[3];
  const float* bn_b   = (const float*)d_in[4];
  const float* cw     = (const float*)d_in[5];
  const float* scale  = (const float*)d_in[6];
  const float* lin_w  = (const float*)d_in[7];
  const float* lin_b  = (const float*)d_in[8];
  float* out = (float*)d_out;
  float* ws  = (float*)d_ws;

  unsigned short* y = (unsigned short*)ws;            // [0, 4194304) floats
  float* S0     = ws + 4194304;                       // 256
  float* bn_acc = ws + 4194560;                       // 256
  float* e_acc  = ws + 4194816;                       // 32768
  unsigned short* w_bf = (unsigned short*)(ws + 4227584);   // 65536 ushorts

  prep<<<64, 256, 0, stream>>>(conv_w, w_bf, S0, e_acc);
  conv_mfma<<<dim3(32, 16), 256, 0, stream>>>(x, w_bf, conv_b, y, bn_acc);
  encode<<<dim3(32, 16), 256, 0, stream>>>(y, bn_acc, bn_g, bn_b, cw, scale, e_acc, S0);
  gscale<<<dim3(32, 16), 256, 0, stream>>>(e_acc, S0, cw, lin_w, lin_b, x, out);
}